// Round 9
// baseline (2560.496 us; speedup 1.0000x reference)
//
#include <hip/hip_runtime.h>
#include <math.h>

#define NN      65536
#define KNN     12
#define WIDTH   256
#define GW      192
#define DEPTH   7
#define GLAYERS 4
#define FF      48

#define KSEG    4            // knn phase-1 split segments
#define SEGLEN  (NN/KSEG)    // 16384 candidates per segment
#define TILE    512          // LDS candidate tile (float4) = 8 KB
#define QCAP    384          // per-query pair capacity (worst-case accepts ~175 +- 13)

// seed grid (SAT): 192^3 cells over [-6,6]^3, cell 0.0625
#define GC    192
#define GC3   7077888
#define GLO   (-6.0f)
#define GCW   0.0625f
#define GINV  16.0f

typedef __attribute__((ext_vector_type(8))) _Float16 half8;
typedef __attribute__((ext_vector_type(4))) _Float16 half4;
typedef __attribute__((ext_vector_type(4))) float    f4;

__device__ __forceinline__ float silu_f(float v) { return v / (1.0f + expf(-v)); }

// top-12 ladder on NAMED scalars (only used in the tiny phase-2 kernel)
#define KSWAP(A,B,IA,IB) do { if (B < A) { float _t=A; A=B; B=_t; int _u=IA; IA=IB; IB=_u; } } while(0)
#define KINSERT(DV,IV) do { b11=(DV); j11=(IV); \
    KSWAP(b10,b11,j10,j11); KSWAP(b9,b10,j9,j10); KSWAP(b8,b9,j8,j9); \
    KSWAP(b7,b8,j7,j8);  KSWAP(b6,b7,j6,j7);  KSWAP(b5,b6,j5,j6); \
    KSWAP(b4,b5,j4,j5);  KSWAP(b3,b4,j3,j4);  KSWAP(b2,b3,j2,j3); \
    KSWAP(b1,b2,j1,j2);  KSWAP(b0,b1,j0,j1); } while(0)

// ---------------- prep: pack x + |x|^2 as float4 ----------------
__global__ __launch_bounds__(256) void prep_xw_kernel(const float* __restrict__ x,
                                                      float4* __restrict__ xw) {
    int i = blockIdx.x * 256 + threadIdx.x;
    float a = x[3*i], b = x[3*i+1], c = x[3*i+2];
    xw[i] = make_float4(a, b, c, a*a + b*b + c*c);
}

// ---------------- seed grid: zero, hist, 3-pass in-place SAT, per-query bound ----------------
__global__ __launch_bounds__(256) void zero_cnt_kernel(int* __restrict__ cnt) {
    int g = blockIdx.x*256 + threadIdx.x;
    *(int4*)&cnt[g*4] = make_int4(0,0,0,0);
}

// grid must be NN/256 blocks: zeroes ALL paircnt entries (0xAA poison -> negative
// atomicAdd slots -> OOB writes was the R8 crash)
__global__ __launch_bounds__(256) void zero_paircnt_kernel(int* __restrict__ pc) {
    pc[blockIdx.x*256 + threadIdx.x] = 0;
}

__device__ __forceinline__ int cell_of(float v) {
    int c = (int)floorf((v - GLO) * GINV);
    return min(max(c, 0), GC-1);
}

__global__ __launch_bounds__(256) void hist_kernel(const float4* __restrict__ xw,
                                                   int* __restrict__ cnt) {
    int i = blockIdx.x*256 + threadIdx.x;
    float4 p = xw[i];
    atomicAdd(&cnt[(cell_of(p.z)*GC + cell_of(p.y))*GC + cell_of(p.x)], 1);
}

__global__ __launch_bounds__(256) void satx_kernel(int* __restrict__ S) {
    int zy = blockIdx.x*256 + threadIdx.x;
    int base = zy * GC, run = 0;
    for (int i = 0; i < GC; ++i) { run += S[base+i]; S[base+i] = run; }
}
__global__ __launch_bounds__(256) void saty_kernel(int* __restrict__ S) {
    int t = blockIdx.x*256 + threadIdx.x;
    int z = t / GC, xx = t % GC, run = 0;
    for (int y = 0; y < GC; ++y) { int idx = (z*GC + y)*GC + xx; run += S[idx]; S[idx] = run; }
}
__global__ __launch_bounds__(256) void satz_kernel(int* __restrict__ S) {
    int t = blockIdx.x*256 + threadIdx.x;
    int y = t / GC, xx = t % GC, run = 0;
    for (int z = 0; z < GC; ++z) { int idx = (z*GC + y)*GC + xx; run += S[idx]; S[idx] = run; }
}

__device__ __forceinline__ int satv(const int* __restrict__ S, int xx, int y, int z) {
    if (xx < 0 || y < 0 || z < 0) return 0;
    return S[(z*GC + y)*GC + xx];
}

__global__ __launch_bounds__(256) void seed_kernel(const float4* __restrict__ xw,
                                                   const int* __restrict__ S,
                                                   float* __restrict__ seed) {
    int q = blockIdx.x*256 + threadIdx.x;
    float4 me = xw[q];
    int cx = cell_of(me.x), cy = cell_of(me.y), cz = cell_of(me.z);
    for (int R = 1; R < GC; ++R) {
        int x0 = max(cx-R, 0), x1 = min(cx+R, GC-1);
        int y0 = max(cy-R, 0), y1 = min(cy+R, GC-1);
        int z0 = max(cz-R, 0), z1 = min(cz+R, GC-1);
        int c = satv(S,x1,y1,z1) - satv(S,x0-1,y1,z1) - satv(S,x1,y0-1,z1) - satv(S,x1,y1,z0-1)
              + satv(S,x0-1,y0-1,z1) + satv(S,x0-1,y1,z0-1) + satv(S,x1,y0-1,z0-1)
              - satv(S,x0-1,y0-1,z0-1);
        if (c >= KNN + 1) {
            float dx = fmaxf(me.x - (GLO + x0*GCW), (GLO + (x1+1)*GCW) - me.x);
            float dy = fmaxf(me.y - (GLO + y0*GCW), (GLO + (y1+1)*GCW) - me.y);
            float dz = fmaxf(me.z - (GLO + z0*GCW), (GLO + (z1+1)*GCW) - me.z);
            seed[q] = (dx*dx + dy*dy + dz*dz) * 1.00002f + 1e-6f;
            return;
        }
    }
    seed[q] = 3e38f;
}

// ---------------- kNN phase 1: ladder-free candidate collection ----------------
__global__ __launch_bounds__(256) void knn_pairs_kernel(const float4* __restrict__ xw,
                                                        const float* __restrict__ seed,
                                                        int* __restrict__ paircnt,
                                                        int* __restrict__ pairs) {
    __shared__ float4 tile[TILE];
    const int tid = threadIdx.x;
    const int q   = blockIdx.x * 256 + tid;
    const int seg = blockIdx.y;
    const float4 me = xw[q];
    const float thr = seed[q] - me.w + 1e-3f;

    for (int t0 = seg*SEGLEN; t0 < (seg+1)*SEGLEN; t0 += TILE) {
        __syncthreads();
        tile[tid]       = xw[t0 + tid];
        tile[tid + 256] = xw[t0 + 256 + tid];
        __syncthreads();
        for (int b = 0; b < TILE; b += 8) {
            float d0,d1,d2,d3,d4,d5,d6,d7;
#define KDIST(U, DV) { float4 c = tile[b + U]; \
        float dot = me.x*c.x + me.y*c.y + me.z*c.z; \
        DV = fmaf(-2.0f, dot, c.w); }
            KDIST(0,d0) KDIST(1,d1) KDIST(2,d2) KDIST(3,d3)
            KDIST(4,d4) KDIST(5,d5) KDIST(6,d6) KDIST(7,d7)
#undef KDIST
#define KACC(U, DV) if (DV < thr) { \
        int slot = atomicAdd(&paircnt[q], 1); \
        if (slot < QCAP) pairs[q*QCAP + slot] = t0 + b + U; }
            KACC(0,d0) KACC(1,d1) KACC(2,d2) KACC(3,d3)
            KACC(4,d4) KACC(5,d5) KACC(6,d6) KACC(7,d7)
#undef KACC
        }
    }
}

// ---------------- kNN phase 2: exact top-12 over survivors ----------------
__global__ __launch_bounds__(256) void knn_topk_kernel(const float4* __restrict__ xw,
                                                       const int* __restrict__ paircnt,
                                                       const int* __restrict__ pairs,
                                                       int* __restrict__ knn_idx) {
    const int q = blockIdx.x * 256 + threadIdx.x;
    const float4 me = xw[q];
    const float qsq = me.w;
    const int n = min(paircnt[q], QCAP);
    float b0=3e38f,b1=3e38f,b2=3e38f,b3=3e38f,b4=3e38f,b5=3e38f,
          b6=3e38f,b7=3e38f,b8=3e38f,b9=3e38f,b10=3e38f,b11=3e38f;
    int   j0=-1,j1=-1,j2=-1,j3=-1,j4=-1,j5=-1,j6=-1,j7=-1,j8=-1,j9=-1,j10=-1,j11=-1;
    for (int i = 0; i < n; ++i) {
        int idx = pairs[q*QCAP + i];
        if (idx == q) continue;                    // self excluded (ref +1e9)
        float4 c = xw[idx];
        float dot = me.x*c.x + me.y*c.y + me.z*c.z;
        float d = fmaf(-2.0f, dot, qsq + c.w);     // EXACT ref formula
        d = fmaxf(d, 0.0f);                        // ref clips at 0
        if (d < b11) KINSERT(d, idx);
    }
    knn_idx[q*KNN+0]=j0;  knn_idx[q*KNN+1]=j1;  knn_idx[q*KNN+2]=j2;
    knn_idx[q*KNN+3]=j3;  knn_idx[q*KNN+4]=j4;  knn_idx[q*KNN+5]=j5;
    knn_idx[q*KNN+6]=j6;  knn_idx[q*KNN+7]=j7;  knn_idx[q*KNN+8]=j8;
    knn_idx[q*KNN+9]=j9;  knn_idx[q*KNN+10]=j10; knn_idx[q*KNN+11]=j11;
}

// ---------------- weight convert+transpose to f16 [N][K] ----------------
__global__ __launch_bounds__(256) void convert_Wt_kernel(const float* __restrict__ W,
                                                         _Float16* __restrict__ Wt) {
    int e = blockIdx.x*256 + threadIdx.x;
    int l = e >> 16, r = e & 65535;
    int n = r >> 8, k = r & 255;
    Wt[(size_t)l*65536 + n*256 + k] = (_Float16)W[(size_t)l*65536 + k*256 + n];
}

__global__ __launch_bounds__(256) void convert_Bg_kernel(const float* __restrict__ Ws,
                                                         const float* __restrict__ Wn,
                                                         _Float16* __restrict__ Bg) {
    int e = blockIdx.x*256 + threadIdx.x;
    int l = e / 73728, r = e % 73728;
    int n = r / 384, k = r % 384;
    float v = (k < 192) ? Ws[(size_t)l*36864 + k*192 + n]
                        : Wn[(size_t)l*36864 + (k-192)*192 + n];
    Bg[(size_t)l*73728 + (size_t)n*384 + k] = (_Float16)v;
}

__global__ __launch_bounds__(256) void convert_Wgo_kernel(const float* __restrict__ Wg_out,
                                                          _Float16* __restrict__ Wgo) {
    int e = blockIdx.x*256 + threadIdx.x;
    int n = e / 192, k = e % 192;
    Wgo[e] = (_Float16)Wg_out[k*256 + n];
}

// ---------------- fourier features + both input layers (f16 out) ----------------
__global__ __launch_bounds__(256) void fourier_input_kernel(
    const float* __restrict__ x, const float* __restrict__ Bf,
    const float* __restrict__ W_in, const float* __restrict__ b_in,
    const float* __restrict__ Wg_in, const float* __restrict__ bg_in,
    _Float16* __restrict__ h0, _Float16* __restrict__ g0) {
    const int n = blockIdx.x * 256 + threadIdx.x;
    const float x0 = x[3*n], x1 = x[3*n+1], x2 = x[3*n+2];
    float ff[FF];
#pragma unroll
    for (int sm = 0; sm < 24; ++sm) {
        int s = sm >> 3, m = sm & 7;
        float p = x0*Bf[s*24 + m] + x1*Bf[s*24 + 8 + m] + x2*Bf[s*24 + 16 + m];
        float sv, cv; sincosf(p, &sv, &cv);
        ff[sm] = sv; ff[24 + sm] = cv;
    }
    {
        const float4* W4 = (const float4*)W_in;
        const float4* b4 = (const float4*)b_in;
#pragma unroll 2
        for (int j4 = 0; j4 < WIDTH/4; ++j4) {
            float4 acc = b4[j4];
#pragma unroll
            for (int k = 0; k < FF; ++k) {
                float4 w = W4[k*(WIDTH/4) + j4]; float f = ff[k];
                acc.x = fmaf(f, w.x, acc.x); acc.y = fmaf(f, w.y, acc.y);
                acc.z = fmaf(f, w.z, acc.z); acc.w = fmaf(f, w.w, acc.w);
            }
            half4 o;
            o[0] = (_Float16)silu_f(acc.x); o[1] = (_Float16)silu_f(acc.y);
            o[2] = (_Float16)silu_f(acc.z); o[3] = (_Float16)silu_f(acc.w);
            *(half4*)&h0[(size_t)n*WIDTH + j4*4] = o;
        }
    }
    {
        const float4* W4 = (const float4*)Wg_in;
        const float4* b4 = (const float4*)bg_in;
#pragma unroll 2
        for (int j4 = 0; j4 < GW/4; ++j4) {
            float4 acc = b4[j4];
#pragma unroll
            for (int k = 0; k < FF; ++k) {
                float4 w = W4[k*(GW/4) + j4]; float f = ff[k];
                acc.x = fmaf(f, w.x, acc.x); acc.y = fmaf(f, w.y, acc.y);
                acc.z = fmaf(f, w.z, acc.z); acc.w = fmaf(f, w.w, acc.w);
            }
            half4 o;
            o[0] = (_Float16)silu_f(acc.x); o[1] = (_Float16)silu_f(acc.y);
            o[2] = (_Float16)silu_f(acc.z); o[3] = (_Float16)silu_f(acc.w);
            *(half4*)&g0[(size_t)n*GW + j4*4] = o;
        }
    }
}

// ---------------- gather + mean over 12 neighbors (f16) ----------------
__global__ __launch_bounds__(192) void gather_mean_kernel(const _Float16* __restrict__ g,
                                                          const int* __restrict__ idx,
                                                          _Float16* __restrict__ agg) {
    __shared__ int nb[KNN];
    const int n = blockIdx.x;
    if (threadIdx.x < KNN) nb[threadIdx.x] = idx[n*KNN + threadIdx.x];
    __syncthreads();
    float acc = 0.0f;
#pragma unroll
    for (int k = 0; k < KNN; ++k) acc += (float)g[(size_t)nb[k]*GW + threadIdx.x];
    agg[(size_t)n*GW + threadIdx.x] = (_Float16)(acc * (1.0f/12.0f));
}

// ---------------- FiLM params ----------------
__global__ __launch_bounds__(256) void film_kernel(const float* __restrict__ cond,
                                                   const float* __restrict__ Wf_g,
                                                   const float* __restrict__ bf_g,
                                                   const float* __restrict__ Wf_b,
                                                   const float* __restrict__ bf_b,
                                                   float* __restrict__ film) {
    const int l = blockIdx.x, j = threadIdx.x;
    float g = bf_g[l*WIDTH + j], b = bf_b[l*WIDTH + j];
    for (int c = 0; c < 64; ++c) {
        float cv = cond[c];
        g = fmaf(cv, Wf_g[(size_t)(l*64 + c)*WIDTH + j], g);
        b = fmaf(cv, Wf_b[(size_t)(l*64 + c)*WIDTH + j], b);
    }
    film[l*2*WIDTH + j]         = 1.0f + g;
    film[l*2*WIDTH + WIDTH + j] = b;
}

// ---------------- f16 MFMA GEMM: BM=128, BN=64, 4 waves ----------------
template<int EPI>
__global__ __launch_bounds__(256) void gemm_mfma(
    const _Float16* __restrict__ A1, const _Float16* __restrict__ A2,
    const _Float16* __restrict__ Bt, int K1, int Ktot, int NC,
    const float* __restrict__ bias, const float* __restrict__ film,
    const _Float16* __restrict__ h0, _Float16* __restrict__ C, int addSkip) {
    __shared__ _Float16 As[128*40];
    __shared__ _Float16 Bs[64*40];
    const int tid = threadIdx.x;
    const int bm = blockIdx.x * 128, bn = blockIdx.y * 64;
    const int wid = tid >> 6, lane = tid & 63;
    const int wm = (wid & 1) * 64, wn = (wid >> 1) * 32;
    const int m16 = lane & 15, kq = lane >> 4;
    const int ar = tid >> 1, ah = tid & 1;
    const int br = tid >> 2, bq = tid & 3;
    f4 acc[4][2];
#pragma unroll
    for (int i = 0; i < 4; ++i)
#pragma unroll
        for (int j = 0; j < 2; ++j) acc[i][j] = (f4){0.f, 0.f, 0.f, 0.f};

    for (int kc = 0; kc < Ktot; kc += 32) {
        const _Float16* Asrc; int kl, ldA;
        if (kc < K1) { Asrc = A1; kl = kc;      ldA = K1; }
        else         { Asrc = A2; kl = kc - K1; ldA = Ktot - K1; }
        {
            const float4* src = (const float4*)&Asrc[(size_t)(bm + ar)*ldA + kl + ah*16];
            *(float4*)&As[ar*40 + ah*16]     = src[0];
            *(float4*)&As[ar*40 + ah*16 + 8] = src[1];
        }
        *(float4*)&Bs[br*40 + bq*8] = *(const float4*)&Bt[(size_t)(bn + br)*Ktot + kc + bq*8];
        __syncthreads();
        half8 af[4], bf[2];
#pragma unroll
        for (int mt = 0; mt < 4; ++mt) af[mt] = *(half8*)&As[(wm + mt*16 + m16)*40 + kq*8];
#pragma unroll
        for (int nt = 0; nt < 2; ++nt) bf[nt] = *(half8*)&Bs[(wn + nt*16 + m16)*40 + kq*8];
#pragma unroll
        for (int mt = 0; mt < 4; ++mt)
#pragma unroll
            for (int nt = 0; nt < 2; ++nt)
                acc[mt][nt] = __builtin_amdgcn_mfma_f32_16x16x32_f16(af[mt], bf[nt], acc[mt][nt], 0, 0, 0);
        __syncthreads();
    }

#pragma unroll
    for (int mt = 0; mt < 4; ++mt) {
#pragma unroll
        for (int nt = 0; nt < 2; ++nt) {
            int col = bn + wn + nt*16 + m16;
#pragma unroll
            for (int r = 0; r < 4; ++r) {
                int row = bm + wm + mt*16 + kq*4 + r;
                float v = acc[mt][nt][r];
                if (EPI == 0) {
                    v = silu_f(v + bias[col]);
                } else if (EPI == 1) {
                    v = fmaf(v + bias[col], film[col], film[NC + col]);
                    v = silu_f(v);
                    if (addSkip) v += (float)h0[(size_t)row*NC + col];
                } else {
                    v += (float)h0[(size_t)row*NC + col];
                }
                C[(size_t)row*NC + col] = (_Float16)v;
            }
        }
    }
}

// ---------------- output head: (h @ W_out + b_out) * 0.01 ----------------
__global__ __launch_bounds__(256) void out_kernel(const _Float16* __restrict__ h,
                                                  const float* __restrict__ W_out,
                                                  const float* __restrict__ b_out,
                                                  float* __restrict__ out) {
    const int n = blockIdx.x * 256 + threadIdx.x;
    float a0 = 0.f, a1 = 0.f, a2 = 0.f;
#pragma unroll 4
    for (int k8 = 0; k8 < WIDTH/8; ++k8) {
        half8 v = *(const half8*)&h[(size_t)n*WIDTH + k8*8];
#pragma unroll
        for (int u = 0; u < 8; ++u) {
            float f = (float)v[u]; int k = k8*8 + u;
            a0 = fmaf(f, W_out[k*3+0], a0);
            a1 = fmaf(f, W_out[k*3+1], a1);
            a2 = fmaf(f, W_out[k*3+2], a2);
        }
    }
    out[n*3+0] = (a0 + b_out[0]) * 0.01f;
    out[n*3+1] = (a1 + b_out[1]) * 0.01f;
    out[n*3+2] = (a2 + b_out[2]) * 0.01f;
}

extern "C" void kernel_launch(void* const* d_in, const int* in_sizes, int n_in,
                              void* d_out, int out_size, void* d_ws, size_t ws_size,
                              hipStream_t stream) {
    const float* x      = (const float*)d_in[0];
    const float* cond   = (const float*)d_in[1];
    const float* Bf     = (const float*)d_in[2];
    const float* W_in   = (const float*)d_in[3];
    const float* b_in   = (const float*)d_in[4];
    const float* Wg_in  = (const float*)d_in[5];
    const float* bg_in  = (const float*)d_in[6];
    const float* Ws     = (const float*)d_in[7];
    const float* Wn     = (const float*)d_in[8];
    const float* bg     = (const float*)d_in[9];
    const float* Wg_out = (const float*)d_in[10];
    const float* W      = (const float*)d_in[11];
    const float* bmlp   = (const float*)d_in[12];
    const float* Wf_g   = (const float*)d_in[13];
    const float* bf_g   = (const float*)d_in[14];
    const float* Wf_b   = (const float*)d_in[15];
    const float* bf_b   = (const float*)d_in[16];
    const float* W_out  = (const float*)d_in[17];
    const float* b_out  = (const float*)d_in[18];
    float* out = (float*)d_out;

    char* ws = (char*)d_ws;
    int*       knn_idx = (int*)      (ws + 0);          //  3,145,728
    float4*    xw      = (float4*)   (ws + 3145728);    //  1,048,576
    float*     film    = (float*)    (ws + 4194304);    //     14,336
    _Float16*  Bg_t    = (_Float16*) (ws + 4210688);    //    589,824
    _Float16*  Wgo_t   = (_Float16*) (ws + 4800512);    //     98,304
    _Float16*  Wt      = (_Float16*) (ws + 4898816);    //    917,504
    _Float16*  h0      = (_Float16*) (ws + 5816320);    // 33,554,432 (f16)
    // SAT + seed overlay h0 region (dead before fourier_input writes h0)
    int*       cnt     = (int*)      (ws + 5816320);    // 28,311,552 (192^3 SAT in place)
    float*     seed    = (float*)    (ws + 34127872);   //    262,144
    _Float16*  g_a     = (_Float16*) (ws + 39370752);   // 25,165,824
    // pairs/paircnt overlay g_a..hA region (all dead during kNN; pairs is
    // NN*QCAP*4 = 100,663,296 B -> 39,370,752..140,034,048; paircnt after it)
    int*       pairs   = (int*)      (ws + 39370752);
    int*       paircnt = (int*)      (ws + 140034048);  //    262,144 -> ends 140,296,192
    _Float16*  g_b     = (_Float16*) (ws + 64536576);   // 25,165,824
    _Float16*  agg     = (_Float16*) (ws + 89702400);   // 25,165,824
    _Float16*  hA      = (_Float16*) (ws + 114868224);  // 33,554,432
    _Float16*  hB      = (_Float16*) (ws + 148422656);  // 33,554,432 -> ends 181,977,088

    // --- kNN: SAT seed -> ladder-free pair collection -> tiny exact top-12 ---
    prep_xw_kernel<<<NN/256, 256, 0, stream>>>(x, xw);
    zero_cnt_kernel<<<GC3/1024, 256, 0, stream>>>(cnt);
    hist_kernel<<<NN/256, 256, 0, stream>>>(xw, cnt);
    satx_kernel<<<GC*GC/256, 256, 0, stream>>>(cnt);
    saty_kernel<<<GC*GC/256, 256, 0, stream>>>(cnt);
    satz_kernel<<<GC*GC/256, 256, 0, stream>>>(cnt);
    seed_kernel<<<NN/256, 256, 0, stream>>>(xw, cnt, seed);
    zero_paircnt_kernel<<<NN/256, 256, 0, stream>>>(paircnt);   // FULL 65536 entries
    knn_pairs_kernel<<<dim3(NN/256, KSEG), 256, 0, stream>>>(xw, seed, paircnt, pairs);
    knn_topk_kernel<<<NN/256, 256, 0, stream>>>(xw, paircnt, pairs, knn_idx);

    // --- network ---
    film_kernel<<<DEPTH, 256, 0, stream>>>(cond, Wf_g, bf_g, Wf_b, bf_b, film);
    convert_Wt_kernel<<<DEPTH*65536/256, 256, 0, stream>>>(W, Wt);
    convert_Bg_kernel<<<GLAYERS*73728/256, 256, 0, stream>>>(Ws, Wn, Bg_t);
    convert_Wgo_kernel<<<256*192/256, 256, 0, stream>>>(Wg_out, Wgo_t);
    fourier_input_kernel<<<NN/256, 256, 0, stream>>>(x, Bf, W_in, b_in, Wg_in, bg_in, h0, g_a);

    _Float16* gin = g_a; _Float16* gout = g_b;
    for (int l = 0; l < GLAYERS; ++l) {
        gather_mean_kernel<<<NN, GW, 0, stream>>>(gin, knn_idx, agg);
        gemm_mfma<0><<<dim3(NN/128, GW/64), 256, 0, stream>>>(
            gin, agg, Bg_t + (size_t)l*73728, GW, 2*GW, GW,
            bg + l*GW, nullptr, nullptr, gout, 0);
        _Float16* t = gin; gin = gout; gout = t;
    }
    // gin == g_a (4 swaps). inject: hA = h0 + gin @ Wg_out
    gemm_mfma<2><<<dim3(NN/128, WIDTH/64), 256, 0, stream>>>(
        gin, nullptr, Wgo_t, GW, GW, WIDTH, nullptr, nullptr, h0, hA, 0);

    _Float16* hin = hA; _Float16* hout = hB;
    for (int l = 0; l < DEPTH; ++l) {
        int skip = (l == 2 || l == 5) ? 1 : 0;   // SKIPS=(3,6): after layers idx 2,5
        gemm_mfma<1><<<dim3(NN/128, WIDTH/64), 256, 0, stream>>>(
            hin, nullptr, Wt + (size_t)l*65536, WIDTH, WIDTH, WIDTH,
            bmlp + l*WIDTH, film + l*2*WIDTH, h0, hout, skip);
        _Float16* t = hin; hin = hout; hout = t;
    }
    out_kernel<<<NN/256, 256, 0, stream>>>(hin, W_out, b_out, out);
}

// Round 10
// 2459.550 us; speedup vs baseline: 1.0410x; 1.0410x over previous
//
#include <hip/hip_runtime.h>
#include <math.h>

#define NN      65536
#define KNN     12
#define WIDTH   256
#define GW      192
#define DEPTH   7
#define GLAYERS 4
#define FF      48

#define QPT     8            // queries per thread (amortize LDS broadcast reads)
#define KSEG    16           // candidate segments
#define SEGLEN  (NN/KSEG)    // 4096 candidates per segment
#define TILE    512          // LDS candidate tile (float4) = 8 KB
#define CAP     40           // per-(q,seg) pair capacity (worst ~16+-3.9, +6sigma)

// seed grid (SAT): 192^3 cells over [-6,6]^3, cell 0.0625
#define GC    192
#define GC3   7077888
#define GLO   (-6.0f)
#define GCW   0.0625f
#define GINV  16.0f

typedef __attribute__((ext_vector_type(8))) _Float16 half8;
typedef __attribute__((ext_vector_type(4))) _Float16 half4;
typedef __attribute__((ext_vector_type(4))) float    f4;

__device__ __forceinline__ float silu_f(float v) { return v / (1.0f + expf(-v)); }

// top-12 ladder on NAMED scalars (phase-2 only)
#define KSWAP(A,B,IA,IB) do { if (B < A) { float _t=A; A=B; B=_t; int _u=IA; IA=IB; IB=_u; } } while(0)
#define KINSERT(DV,IV) do { b11=(DV); j11=(IV); \
    KSWAP(b10,b11,j10,j11); KSWAP(b9,b10,j9,j10); KSWAP(b8,b9,j8,j9); \
    KSWAP(b7,b8,j7,j8);  KSWAP(b6,b7,j6,j7);  KSWAP(b5,b6,j5,j6); \
    KSWAP(b4,b5,j4,j5);  KSWAP(b3,b4,j3,j4);  KSWAP(b2,b3,j2,j3); \
    KSWAP(b1,b2,j1,j2);  KSWAP(b0,b1,j0,j1); } while(0)

// ---------------- prep: pack x + |x|^2 as float4 ----------------
__global__ __launch_bounds__(256) void prep_xw_kernel(const float* __restrict__ x,
                                                      float4* __restrict__ xw) {
    int i = blockIdx.x * 256 + threadIdx.x;
    float a = x[3*i], b = x[3*i+1], c = x[3*i+2];
    xw[i] = make_float4(a, b, c, a*a + b*b + c*c);
}

// ---------------- seed grid: zero, hist, 3-pass in-place SAT, per-query bound ----------------
__global__ __launch_bounds__(256) void zero_cnt_kernel(int* __restrict__ cnt) {
    int g = blockIdx.x*256 + threadIdx.x;
    *(int4*)&cnt[g*4] = make_int4(0,0,0,0);
}

__device__ __forceinline__ int cell_of(float v) {
    int c = (int)floorf((v - GLO) * GINV);
    return min(max(c, 0), GC-1);
}

__global__ __launch_bounds__(256) void hist_kernel(const float4* __restrict__ xw,
                                                   int* __restrict__ cnt) {
    int i = blockIdx.x*256 + threadIdx.x;
    float4 p = xw[i];
    atomicAdd(&cnt[(cell_of(p.z)*GC + cell_of(p.y))*GC + cell_of(p.x)], 1);
}

__global__ __launch_bounds__(256) void satx_kernel(int* __restrict__ S) {
    int zy = blockIdx.x*256 + threadIdx.x;
    int base = zy * GC, run = 0;
    for (int i = 0; i < GC; ++i) { run += S[base+i]; S[base+i] = run; }
}
__global__ __launch_bounds__(256) void saty_kernel(int* __restrict__ S) {
    int t = blockIdx.x*256 + threadIdx.x;
    int z = t / GC, xx = t % GC, run = 0;
    for (int y = 0; y < GC; ++y) { int idx = (z*GC + y)*GC + xx; run += S[idx]; S[idx] = run; }
}
__global__ __launch_bounds__(256) void satz_kernel(int* __restrict__ S) {
    int t = blockIdx.x*256 + threadIdx.x;
    int y = t / GC, xx = t % GC, run = 0;
    for (int z = 0; z < GC; ++z) { int idx = (z*GC + y)*GC + xx; run += S[idx]; S[idx] = run; }
}

__device__ __forceinline__ int satv(const int* __restrict__ S, int xx, int y, int z) {
    if (xx < 0 || y < 0 || z < 0) return 0;
    return S[(z*GC + y)*GC + xx];
}

__global__ __launch_bounds__(256) void seed_kernel(const float4* __restrict__ xw,
                                                   const int* __restrict__ S,
                                                   float* __restrict__ seed) {
    int q = blockIdx.x*256 + threadIdx.x;
    float4 me = xw[q];
    int cx = cell_of(me.x), cy = cell_of(me.y), cz = cell_of(me.z);
    for (int R = 1; R < GC; ++R) {
        int x0 = max(cx-R, 0), x1 = min(cx+R, GC-1);
        int y0 = max(cy-R, 0), y1 = min(cy+R, GC-1);
        int z0 = max(cz-R, 0), z1 = min(cz+R, GC-1);
        int c = satv(S,x1,y1,z1) - satv(S,x0-1,y1,z1) - satv(S,x1,y0-1,z1) - satv(S,x1,y1,z0-1)
              + satv(S,x0-1,y0-1,z1) + satv(S,x0-1,y1,z0-1) + satv(S,x1,y0-1,z0-1)
              - satv(S,x0-1,y0-1,z0-1);
        if (c >= KNN + 1) {
            float dx = fmaxf(me.x - (GLO + x0*GCW), (GLO + (x1+1)*GCW) - me.x);
            float dy = fmaxf(me.y - (GLO + y0*GCW), (GLO + (y1+1)*GCW) - me.y);
            float dz = fmaxf(me.z - (GLO + z0*GCW), (GLO + (z1+1)*GCW) - me.z);
            seed[q] = (dx*dx + dy*dy + dz*dz) * 1.00002f + 1e-6f;
            return;
        }
    }
    seed[q] = 3e38f;
}

// ---------------- kNN phase 1: QPT=8 queries/thread, no atomics ----------------
// accept iff c.w - 2*me.c < thr  <=>  me.c - 0.5*c.w > -0.5*thr = ht
// each (q,seg) has a private u16 list + register counter -> no atomics, no ladder.
#define FORQ(OP) OP(0) OP(1) OP(2) OP(3) OP(4) OP(5) OP(6) OP(7)

__global__ __launch_bounds__(256) void knn_pairs_kernel(const float4* __restrict__ xw,
                                                        const float* __restrict__ seed,
                                                        unsigned short* __restrict__ pairs,
                                                        unsigned char* __restrict__ cnt8) {
    __shared__ float4 tile[TILE];
    const int tid = threadIdx.x;
    const int qb  = blockIdx.x * (256*QPT);   // 2048 queries per block
    const int seg = blockIdx.y;

#define DECLQ(u) float mex##u, mey##u, mez##u, ht##u; int cnt##u = 0, bas##u;
    FORQ(DECLQ)
#undef DECLQ
#define LOADQ(u) { int qq = qb + u*256 + tid; float4 m = xw[qq]; \
    mex##u = m.x; mey##u = m.y; mez##u = m.z; \
    ht##u = -0.5f*(seed[qq] - m.w + 1e-3f); \
    bas##u = (qq*KSEG + seg)*CAP; }
    FORQ(LOADQ)
#undef LOADQ

    for (int t0 = seg*SEGLEN; t0 < (seg+1)*SEGLEN; t0 += TILE) {
        __syncthreads();
        tile[tid]       = xw[t0 + tid];
        tile[tid + 256] = xw[t0 + 256 + tid];
        __syncthreads();
#pragma unroll 2
        for (int j = 0; j < TILE; ++j) {
            float4 c = tile[j];                   // wave-uniform: 1 broadcast b128
            float nh = -0.5f * c.w;
            int jg = t0 + j;
#define DISTQ(u) { float s = fmaf(mex##u, c.x, fmaf(mey##u, c.y, fmaf(mez##u, c.z, nh))); \
        if (s > ht##u) { if (cnt##u < CAP) pairs[bas##u + cnt##u] = (unsigned short)jg; ++cnt##u; } }
            FORQ(DISTQ)
#undef DISTQ
        }
    }
#define STQ(u) cnt8[(qb + u*256 + tid)*KSEG + seg] = (unsigned char)(cnt##u < CAP ? cnt##u : CAP);
    FORQ(STQ)
#undef STQ
}

// ---------------- kNN phase 2: exact top-12 over survivors ----------------
__global__ __launch_bounds__(256) void knn_topk_kernel(const float4* __restrict__ xw,
                                                       const unsigned char* __restrict__ cnt8,
                                                       const unsigned short* __restrict__ pairs,
                                                       int* __restrict__ knn_idx) {
    const int q = blockIdx.x * 256 + threadIdx.x;
    const float4 me = xw[q];
    const float qsq = me.w;
    float b0=3e38f,b1=3e38f,b2=3e38f,b3=3e38f,b4=3e38f,b5=3e38f,
          b6=3e38f,b7=3e38f,b8=3e38f,b9=3e38f,b10=3e38f,b11=3e38f;
    int   j0=-1,j1=-1,j2=-1,j3=-1,j4=-1,j5=-1,j6=-1,j7=-1,j8=-1,j9=-1,j10=-1,j11=-1;
    for (int s = 0; s < KSEG; ++s) {
        const int n = cnt8[q*KSEG + s];
        const int base = (q*KSEG + s)*CAP;
        for (int i = 0; i < n; ++i) {
            int idx = pairs[base + i];
            if (idx == q) continue;                // self excluded (ref +1e9)
            float4 c = xw[idx];
            float dot = me.x*c.x + me.y*c.y + me.z*c.z;
            float d = fmaf(-2.0f, dot, qsq + c.w); // EXACT ref formula
            d = fmaxf(d, 0.0f);                    // ref clips at 0
            if (d < b11) KINSERT(d, idx);
        }
    }
    knn_idx[q*KNN+0]=j0;  knn_idx[q*KNN+1]=j1;  knn_idx[q*KNN+2]=j2;
    knn_idx[q*KNN+3]=j3;  knn_idx[q*KNN+4]=j4;  knn_idx[q*KNN+5]=j5;
    knn_idx[q*KNN+6]=j6;  knn_idx[q*KNN+7]=j7;  knn_idx[q*KNN+8]=j8;
    knn_idx[q*KNN+9]=j9;  knn_idx[q*KNN+10]=j10; knn_idx[q*KNN+11]=j11;
}

// ---------------- weight convert+transpose to f16 [N][K] ----------------
__global__ __launch_bounds__(256) void convert_Wt_kernel(const float* __restrict__ W,
                                                         _Float16* __restrict__ Wt) {
    int e = blockIdx.x*256 + threadIdx.x;
    int l = e >> 16, r = e & 65535;
    int n = r >> 8, k = r & 255;
    Wt[(size_t)l*65536 + n*256 + k] = (_Float16)W[(size_t)l*65536 + k*256 + n];
}

__global__ __launch_bounds__(256) void convert_Bg_kernel(const float* __restrict__ Ws,
                                                         const float* __restrict__ Wn,
                                                         _Float16* __restrict__ Bg) {
    int e = blockIdx.x*256 + threadIdx.x;
    int l = e / 73728, r = e % 73728;
    int n = r / 384, k = r % 384;
    float v = (k < 192) ? Ws[(size_t)l*36864 + k*192 + n]
                        : Wn[(size_t)l*36864 + (k-192)*192 + n];
    Bg[(size_t)l*73728 + (size_t)n*384 + k] = (_Float16)v;
}

__global__ __launch_bounds__(256) void convert_Wgo_kernel(const float* __restrict__ Wg_out,
                                                          _Float16* __restrict__ Wgo) {
    int e = blockIdx.x*256 + threadIdx.x;
    int n = e / 192, k = e % 192;
    Wgo[e] = (_Float16)Wg_out[k*256 + n];
}

// ---------------- fourier features + both input layers (f16 out) ----------------
__global__ __launch_bounds__(256) void fourier_input_kernel(
    const float* __restrict__ x, const float* __restrict__ Bf,
    const float* __restrict__ W_in, const float* __restrict__ b_in,
    const float* __restrict__ Wg_in, const float* __restrict__ bg_in,
    _Float16* __restrict__ h0, _Float16* __restrict__ g0) {
    const int n = blockIdx.x * 256 + threadIdx.x;
    const float x0 = x[3*n], x1 = x[3*n+1], x2 = x[3*n+2];
    float ff[FF];
#pragma unroll
    for (int sm = 0; sm < 24; ++sm) {
        int s = sm >> 3, m = sm & 7;
        float p = x0*Bf[s*24 + m] + x1*Bf[s*24 + 8 + m] + x2*Bf[s*24 + 16 + m];
        float sv, cv; sincosf(p, &sv, &cv);
        ff[sm] = sv; ff[24 + sm] = cv;
    }
    {
        const float4* W4 = (const float4*)W_in;
        const float4* b4 = (const float4*)b_in;
#pragma unroll 2
        for (int j4 = 0; j4 < WIDTH/4; ++j4) {
            float4 acc = b4[j4];
#pragma unroll
            for (int k = 0; k < FF; ++k) {
                float4 w = W4[k*(WIDTH/4) + j4]; float f = ff[k];
                acc.x = fmaf(f, w.x, acc.x); acc.y = fmaf(f, w.y, acc.y);
                acc.z = fmaf(f, w.z, acc.z); acc.w = fmaf(f, w.w, acc.w);
            }
            half4 o;
            o[0] = (_Float16)silu_f(acc.x); o[1] = (_Float16)silu_f(acc.y);
            o[2] = (_Float16)silu_f(acc.z); o[3] = (_Float16)silu_f(acc.w);
            *(half4*)&h0[(size_t)n*WIDTH + j4*4] = o;
        }
    }
    {
        const float4* W4 = (const float4*)Wg_in;
        const float4* b4 = (const float4*)bg_in;
#pragma unroll 2
        for (int j4 = 0; j4 < GW/4; ++j4) {
            float4 acc = b4[j4];
#pragma unroll
            for (int k = 0; k < FF; ++k) {
                float4 w = W4[k*(GW/4) + j4]; float f = ff[k];
                acc.x = fmaf(f, w.x, acc.x); acc.y = fmaf(f, w.y, acc.y);
                acc.z = fmaf(f, w.z, acc.z); acc.w = fmaf(f, w.w, acc.w);
            }
            half4 o;
            o[0] = (_Float16)silu_f(acc.x); o[1] = (_Float16)silu_f(acc.y);
            o[2] = (_Float16)silu_f(acc.z); o[3] = (_Float16)silu_f(acc.w);
            *(half4*)&g0[(size_t)n*GW + j4*4] = o;
        }
    }
}

// ---------------- gather + mean over 12 neighbors (f16) ----------------
__global__ __launch_bounds__(192) void gather_mean_kernel(const _Float16* __restrict__ g,
                                                          const int* __restrict__ idx,
                                                          _Float16* __restrict__ agg) {
    __shared__ int nb[KNN];
    const int n = blockIdx.x;
    if (threadIdx.x < KNN) nb[threadIdx.x] = idx[n*KNN + threadIdx.x];
    __syncthreads();
    float acc = 0.0f;
#pragma unroll
    for (int k = 0; k < KNN; ++k) acc += (float)g[(size_t)nb[k]*GW + threadIdx.x];
    agg[(size_t)n*GW + threadIdx.x] = (_Float16)(acc * (1.0f/12.0f));
}

// ---------------- FiLM params ----------------
__global__ __launch_bounds__(256) void film_kernel(const float* __restrict__ cond,
                                                   const float* __restrict__ Wf_g,
                                                   const float* __restrict__ bf_g,
                                                   const float* __restrict__ Wf_b,
                                                   const float* __restrict__ bf_b,
                                                   float* __restrict__ film) {
    const int l = blockIdx.x, j = threadIdx.x;
    float g = bf_g[l*WIDTH + j], b = bf_b[l*WIDTH + j];
    for (int c = 0; c < 64; ++c) {
        float cv = cond[c];
        g = fmaf(cv, Wf_g[(size_t)(l*64 + c)*WIDTH + j], g);
        b = fmaf(cv, Wf_b[(size_t)(l*64 + c)*WIDTH + j], b);
    }
    film[l*2*WIDTH + j]         = 1.0f + g;
    film[l*2*WIDTH + WIDTH + j] = b;
}

// ---------------- f16 MFMA GEMM: BM=128, BN=64, 4 waves ----------------
template<int EPI>
__global__ __launch_bounds__(256) void gemm_mfma(
    const _Float16* __restrict__ A1, const _Float16* __restrict__ A2,
    const _Float16* __restrict__ Bt, int K1, int Ktot, int NC,
    const float* __restrict__ bias, const float* __restrict__ film,
    const _Float16* __restrict__ h0, _Float16* __restrict__ C, int addSkip) {
    __shared__ _Float16 As[128*40];
    __shared__ _Float16 Bs[64*40];
    const int tid = threadIdx.x;
    const int bm = blockIdx.x * 128, bn = blockIdx.y * 64;
    const int wid = tid >> 6, lane = tid & 63;
    const int wm = (wid & 1) * 64, wn = (wid >> 1) * 32;
    const int m16 = lane & 15, kq = lane >> 4;
    const int ar = tid >> 1, ah = tid & 1;
    const int br = tid >> 2, bq = tid & 3;
    f4 acc[4][2];
#pragma unroll
    for (int i = 0; i < 4; ++i)
#pragma unroll
        for (int j = 0; j < 2; ++j) acc[i][j] = (f4){0.f, 0.f, 0.f, 0.f};

    for (int kc = 0; kc < Ktot; kc += 32) {
        const _Float16* Asrc; int kl, ldA;
        if (kc < K1) { Asrc = A1; kl = kc;      ldA = K1; }
        else         { Asrc = A2; kl = kc - K1; ldA = Ktot - K1; }
        {
            const float4* src = (const float4*)&Asrc[(size_t)(bm + ar)*ldA + kl + ah*16];
            *(float4*)&As[ar*40 + ah*16]     = src[0];
            *(float4*)&As[ar*40 + ah*16 + 8] = src[1];
        }
        *(float4*)&Bs[br*40 + bq*8] = *(const float4*)&Bt[(size_t)(bn + br)*Ktot + kc + bq*8];
        __syncthreads();
        half8 af[4], bf[2];
#pragma unroll
        for (int mt = 0; mt < 4; ++mt) af[mt] = *(half8*)&As[(wm + mt*16 + m16)*40 + kq*8];
#pragma unroll
        for (int nt = 0; nt < 2; ++nt) bf[nt] = *(half8*)&Bs[(wn + nt*16 + m16)*40 + kq*8];
#pragma unroll
        for (int mt = 0; mt < 4; ++mt)
#pragma unroll
            for (int nt = 0; nt < 2; ++nt)
                acc[mt][nt] = __builtin_amdgcn_mfma_f32_16x16x32_f16(af[mt], bf[nt], acc[mt][nt], 0, 0, 0);
        __syncthreads();
    }

#pragma unroll
    for (int mt = 0; mt < 4; ++mt) {
#pragma unroll
        for (int nt = 0; nt < 2; ++nt) {
            int col = bn + wn + nt*16 + m16;
#pragma unroll
            for (int r = 0; r < 4; ++r) {
                int row = bm + wm + mt*16 + kq*4 + r;
                float v = acc[mt][nt][r];
                if (EPI == 0) {
                    v = silu_f(v + bias[col]);
                } else if (EPI == 1) {
                    v = fmaf(v + bias[col], film[col], film[NC + col]);
                    v = silu_f(v);
                    if (addSkip) v += (float)h0[(size_t)row*NC + col];
                } else {
                    v += (float)h0[(size_t)row*NC + col];
                }
                C[(size_t)row*NC + col] = (_Float16)v;
            }
        }
    }
}

// ---------------- output head: (h @ W_out + b_out) * 0.01 ----------------
__global__ __launch_bounds__(256) void out_kernel(const _Float16* __restrict__ h,
                                                  const float* __restrict__ W_out,
                                                  const float* __restrict__ b_out,
                                                  float* __restrict__ out) {
    const int n = blockIdx.x * 256 + threadIdx.x;
    float a0 = 0.f, a1 = 0.f, a2 = 0.f;
#pragma unroll 4
    for (int k8 = 0; k8 < WIDTH/8; ++k8) {
        half8 v = *(const half8*)&h[(size_t)n*WIDTH + k8*8];
#pragma unroll
        for (int u = 0; u < 8; ++u) {
            float f = (float)v[u]; int k = k8*8 + u;
            a0 = fmaf(f, W_out[k*3+0], a0);
            a1 = fmaf(f, W_out[k*3+1], a1);
            a2 = fmaf(f, W_out[k*3+2], a2);
        }
    }
    out[n*3+0] = (a0 + b_out[0]) * 0.01f;
    out[n*3+1] = (a1 + b_out[1]) * 0.01f;
    out[n*3+2] = (a2 + b_out[2]) * 0.01f;
}

extern "C" void kernel_launch(void* const* d_in, const int* in_sizes, int n_in,
                              void* d_out, int out_size, void* d_ws, size_t ws_size,
                              hipStream_t stream) {
    const float* x      = (const float*)d_in[0];
    const float* cond   = (const float*)d_in[1];
    const float* Bf     = (const float*)d_in[2];
    const float* W_in   = (const float*)d_in[3];
    const float* b_in   = (const float*)d_in[4];
    const float* Wg_in  = (const float*)d_in[5];
    const float* bg_in  = (const float*)d_in[6];
    const float* Ws     = (const float*)d_in[7];
    const float* Wn     = (const float*)d_in[8];
    const float* bg     = (const float*)d_in[9];
    const float* Wg_out = (const float*)d_in[10];
    const float* W      = (const float*)d_in[11];
    const float* bmlp   = (const float*)d_in[12];
    const float* Wf_g   = (const float*)d_in[13];
    const float* bf_g   = (const float*)d_in[14];
    const float* Wf_b   = (const float*)d_in[15];
    const float* bf_b   = (const float*)d_in[16];
    const float* W_out  = (const float*)d_in[17];
    const float* b_out  = (const float*)d_in[18];
    float* out = (float*)d_out;

    char* ws = (char*)d_ws;
    int*       knn_idx = (int*)      (ws + 0);          //  3,145,728
    float4*    xw      = (float4*)   (ws + 3145728);    //  1,048,576
    float*     film    = (float*)    (ws + 4194304);    //     14,336
    _Float16*  Bg_t    = (_Float16*) (ws + 4210688);    //    589,824
    _Float16*  Wgo_t   = (_Float16*) (ws + 4800512);    //     98,304
    _Float16*  Wt      = (_Float16*) (ws + 4898816);    //    917,504
    _Float16*  h0      = (_Float16*) (ws + 5816320);    // 33,554,432 (f16)
    // SAT + seed overlay h0 region (dead before fourier_input writes h0)
    int*       cnt     = (int*)      (ws + 5816320);    // 28,311,552 (192^3 SAT in place)
    float*     seed    = (float*)    (ws + 34127872);   //    262,144
    _Float16*  g_a     = (_Float16*) (ws + 39370752);   // 25,165,824
    // pairs/cnt8 overlay g_a..hB region (all dead during kNN):
    // pairs u16: NN*KSEG*CAP*2 = 83,886,080 -> 39,370,752..123,256,832
    unsigned short* pairs = (unsigned short*)(ws + 39370752);
    unsigned char*  cnt8  = (unsigned char*) (ws + 123256832);  // 1,048,576
    _Float16*  g_b     = (_Float16*) (ws + 64536576);   // 25,165,824
    _Float16*  agg     = (_Float16*) (ws + 89702400);   // 25,165,824
    _Float16*  hA      = (_Float16*) (ws + 114868224);  // 33,554,432
    _Float16*  hB      = (_Float16*) (ws + 148422656);  // 33,554,432 -> ends 181,977,088

    // --- kNN: SAT seed -> QPT=8 pair scan (no atomics) -> tiny exact top-12 ---
    prep_xw_kernel<<<NN/256, 256, 0, stream>>>(x, xw);
    zero_cnt_kernel<<<GC3/1024, 256, 0, stream>>>(cnt);
    hist_kernel<<<NN/256, 256, 0, stream>>>(xw, cnt);
    satx_kernel<<<GC*GC/256, 256, 0, stream>>>(cnt);
    saty_kernel<<<GC*GC/256, 256, 0, stream>>>(cnt);
    satz_kernel<<<GC*GC/256, 256, 0, stream>>>(cnt);
    seed_kernel<<<NN/256, 256, 0, stream>>>(xw, cnt, seed);
    knn_pairs_kernel<<<dim3(NN/(256*QPT), KSEG), 256, 0, stream>>>(xw, seed, pairs, cnt8);
    knn_topk_kernel<<<NN/256, 256, 0, stream>>>(xw, cnt8, pairs, knn_idx);

    // --- network ---
    film_kernel<<<DEPTH, 256, 0, stream>>>(cond, Wf_g, bf_g, Wf_b, bf_b, film);
    convert_Wt_kernel<<<DEPTH*65536/256, 256, 0, stream>>>(W, Wt);
    convert_Bg_kernel<<<GLAYERS*73728/256, 256, 0, stream>>>(Ws, Wn, Bg_t);
    convert_Wgo_kernel<<<256*192/256, 256, 0, stream>>>(Wg_out, Wgo_t);
    fourier_input_kernel<<<NN/256, 256, 0, stream>>>(x, Bf, W_in, b_in, Wg_in, bg_in, h0, g_a);

    _Float16* gin = g_a; _Float16* gout = g_b;
    for (int l = 0; l < GLAYERS; ++l) {
        gather_mean_kernel<<<NN, GW, 0, stream>>>(gin, knn_idx, agg);
        gemm_mfma<0><<<dim3(NN/128, GW/64), 256, 0, stream>>>(
            gin, agg, Bg_t + (size_t)l*73728, GW, 2*GW, GW,
            bg + l*GW, nullptr, nullptr, gout, 0);
        _Float16* t = gin; gin = gout; gout = t;
    }
    // gin == g_a (4 swaps). inject: hA = h0 + gin @ Wg_out
    gemm_mfma<2><<<dim3(NN/128, WIDTH/64), 256, 0, stream>>>(
        gin, nullptr, Wgo_t, GW, GW, WIDTH, nullptr, nullptr, h0, hA, 0);

    _Float16* hin = hA; _Float16* hout = hB;
    for (int l = 0; l < DEPTH; ++l) {
        int skip = (l == 2 || l == 5) ? 1 : 0;   // SKIPS=(3,6): after layers idx 2,5
        gemm_mfma<1><<<dim3(NN/128, WIDTH/64), 256, 0, stream>>>(
            hin, nullptr, Wt + (size_t)l*65536, WIDTH, WIDTH, WIDTH,
            bmlp + l*WIDTH, film + l*2*WIDTH, h0, hout, skip);
        _Float16* t = hin; hin = hout; hout = t;
    }
    out_kernel<<<NN/256, 256, 0, stream>>>(hin, W_out, b_out, out);
}

// Round 11
// 1884.909 us; speedup vs baseline: 1.3584x; 1.3049x over previous
//
#include <hip/hip_runtime.h>
#include <math.h>

#define NN      65536
#define KNN     12
#define WIDTH   256
#define GW      192
#define DEPTH   7
#define GLAYERS 4
#define FF      48

#define QPT     8            // queries per thread (amortize LDS broadcast reads)
#define KSEG    32           // candidate segments (4 blocks/CU -> 50% occupancy)
#define SEGLEN  (NN/KSEG)    // 2048 candidates per segment
#define TILE    512          // LDS candidate tile (float4) = 8 KB
#define CAP     28           // per-(q,seg) capacity (Binom(~177,1/32): mean 5.5, +9sigma)

// seed grid (SAT): 192^3 cells over [-6,6]^3, cell 0.0625
#define GC    192
#define GC3   7077888
#define GLO   (-6.0f)
#define GCW   0.0625f
#define GINV  16.0f

typedef __attribute__((ext_vector_type(8))) _Float16 half8;
typedef __attribute__((ext_vector_type(4))) _Float16 half4;
typedef __attribute__((ext_vector_type(4))) float    f4;

__device__ __forceinline__ float silu_f(float v) { return v / (1.0f + expf(-v)); }

// top-12 ladder on NAMED scalars (phase-2 only)
#define KSWAP(A,B,IA,IB) do { if (B < A) { float _t=A; A=B; B=_t; int _u=IA; IA=IB; IB=_u; } } while(0)
#define KINSERT(DV,IV) do { b11=(DV); j11=(IV); \
    KSWAP(b10,b11,j10,j11); KSWAP(b9,b10,j9,j10); KSWAP(b8,b9,j8,j9); \
    KSWAP(b7,b8,j7,j8);  KSWAP(b6,b7,j6,j7);  KSWAP(b5,b6,j5,j6); \
    KSWAP(b4,b5,j4,j5);  KSWAP(b3,b4,j3,j4);  KSWAP(b2,b3,j2,j3); \
    KSWAP(b1,b2,j1,j2);  KSWAP(b0,b1,j0,j1); } while(0)

// ---------------- prep: pack x + |x|^2 as float4 ----------------
__global__ __launch_bounds__(256) void prep_xw_kernel(const float* __restrict__ x,
                                                      float4* __restrict__ xw) {
    int i = blockIdx.x * 256 + threadIdx.x;
    float a = x[3*i], b = x[3*i+1], c = x[3*i+2];
    xw[i] = make_float4(a, b, c, a*a + b*b + c*c);
}

// ---------------- seed grid: zero, hist, 3-pass in-place SAT, per-query bound ----------------
__global__ __launch_bounds__(256) void zero_cnt_kernel(int* __restrict__ cnt) {
    int g = blockIdx.x*256 + threadIdx.x;
    *(int4*)&cnt[g*4] = make_int4(0,0,0,0);
}

__device__ __forceinline__ int cell_of(float v) {
    int c = (int)floorf((v - GLO) * GINV);
    return min(max(c, 0), GC-1);
}

__global__ __launch_bounds__(256) void hist_kernel(const float4* __restrict__ xw,
                                                   int* __restrict__ cnt) {
    int i = blockIdx.x*256 + threadIdx.x;
    float4 p = xw[i];
    atomicAdd(&cnt[(cell_of(p.z)*GC + cell_of(p.y))*GC + cell_of(p.x)], 1);
}

__global__ __launch_bounds__(256) void satx_kernel(int* __restrict__ S) {
    int zy = blockIdx.x*256 + threadIdx.x;
    int base = zy * GC, run = 0;
    for (int i = 0; i < GC; ++i) { run += S[base+i]; S[base+i] = run; }
}
__global__ __launch_bounds__(256) void saty_kernel(int* __restrict__ S) {
    int t = blockIdx.x*256 + threadIdx.x;
    int z = t / GC, xx = t % GC, run = 0;
    for (int y = 0; y < GC; ++y) { int idx = (z*GC + y)*GC + xx; run += S[idx]; S[idx] = run; }
}
__global__ __launch_bounds__(256) void satz_kernel(int* __restrict__ S) {
    int t = blockIdx.x*256 + threadIdx.x;
    int y = t / GC, xx = t % GC, run = 0;
    for (int z = 0; z < GC; ++z) { int idx = (z*GC + y)*GC + xx; run += S[idx]; S[idx] = run; }
}

__device__ __forceinline__ int satv(const int* __restrict__ S, int xx, int y, int z) {
    if (xx < 0 || y < 0 || z < 0) return 0;
    return S[(z*GC + y)*GC + xx];
}

__global__ __launch_bounds__(256) void seed_kernel(const float4* __restrict__ xw,
                                                   const int* __restrict__ S,
                                                   float* __restrict__ seed) {
    int q = blockIdx.x*256 + threadIdx.x;
    float4 me = xw[q];
    int cx = cell_of(me.x), cy = cell_of(me.y), cz = cell_of(me.z);
    for (int R = 1; R < GC; ++R) {
        int x0 = max(cx-R, 0), x1 = min(cx+R, GC-1);
        int y0 = max(cy-R, 0), y1 = min(cy+R, GC-1);
        int z0 = max(cz-R, 0), z1 = min(cz+R, GC-1);
        int c = satv(S,x1,y1,z1) - satv(S,x0-1,y1,z1) - satv(S,x1,y0-1,z1) - satv(S,x1,y1,z0-1)
              + satv(S,x0-1,y0-1,z1) + satv(S,x0-1,y1,z0-1) + satv(S,x1,y0-1,z0-1)
              - satv(S,x0-1,y0-1,z0-1);
        if (c >= KNN + 1) {
            float dx = fmaxf(me.x - (GLO + x0*GCW), (GLO + (x1+1)*GCW) - me.x);
            float dy = fmaxf(me.y - (GLO + y0*GCW), (GLO + (y1+1)*GCW) - me.y);
            float dz = fmaxf(me.z - (GLO + z0*GCW), (GLO + (z1+1)*GCW) - me.z);
            seed[q] = (dx*dx + dy*dy + dz*dz) * 1.00002f + 1e-6f;
            return;
        }
    }
    seed[q] = 3e38f;
}

// ---------------- kNN phase 1: QPT=8 queries/thread, dense writes ----------------
// accept iff c.w - 2*me.c < thr  <=>  me.c - 0.5*c.w > -0.5*thr = ht
// pairs layout [seg][q][CAP]: adjacent lanes write 56 B apart -> wave's accepts
// land in a ~3.6 KB window (coalesced lines), vs 82 KB scatter in the old
// [q][seg] layout (R10: 193 MB RMW write traffic at 153 GB/s == kernel time).
#define FORQ(OP) OP(0) OP(1) OP(2) OP(3) OP(4) OP(5) OP(6) OP(7)

__global__ __launch_bounds__(256) void knn_pairs_kernel(const float4* __restrict__ xw,
                                                        const float* __restrict__ seed,
                                                        unsigned short* __restrict__ pairs,
                                                        unsigned char* __restrict__ cnt8) {
    __shared__ float4 tile[TILE];
    const int tid = threadIdx.x;
    const int qb  = blockIdx.x * (256*QPT);   // 2048 queries per block
    const int seg = blockIdx.y;

#define DECLQ(u) float mex##u, mey##u, mez##u, ht##u; int cnt##u = 0; size_t bas##u;
    FORQ(DECLQ)
#undef DECLQ
#define LOADQ(u) { int qq = qb + u*256 + tid; float4 m = xw[qq]; \
    mex##u = m.x; mey##u = m.y; mez##u = m.z; \
    ht##u = -0.5f*(seed[qq] - m.w + 1e-3f); \
    bas##u = ((size_t)seg*NN + qq)*CAP; }
    FORQ(LOADQ)
#undef LOADQ

    for (int t0 = seg*SEGLEN; t0 < (seg+1)*SEGLEN; t0 += TILE) {
        __syncthreads();
        tile[tid]       = xw[t0 + tid];
        tile[tid + 256] = xw[t0 + 256 + tid];
        __syncthreads();
#pragma unroll 2
        for (int j = 0; j < TILE; ++j) {
            float4 c = tile[j];                   // wave-uniform: 1 broadcast b128
            float nh = -0.5f * c.w;
            int jg = t0 + j;
#define DISTQ(u) { float s = fmaf(mex##u, c.x, fmaf(mey##u, c.y, fmaf(mez##u, c.z, nh))); \
        if (s > ht##u) { if (cnt##u < CAP) pairs[bas##u + cnt##u] = (unsigned short)jg; ++cnt##u; } }
            FORQ(DISTQ)
#undef DISTQ
        }
    }
#define STQ(u) cnt8[(size_t)seg*NN + (qb + u*256 + tid)] = (unsigned char)(cnt##u < CAP ? cnt##u : CAP);
    FORQ(STQ)
#undef STQ
}

// ---------------- kNN phase 2: exact top-12 over survivors ----------------
__global__ __launch_bounds__(256) void knn_topk_kernel(const float4* __restrict__ xw,
                                                       const unsigned char* __restrict__ cnt8,
                                                       const unsigned short* __restrict__ pairs,
                                                       int* __restrict__ knn_idx) {
    const int q = blockIdx.x * 256 + threadIdx.x;
    const float4 me = xw[q];
    const float qsq = me.w;
    float b0=3e38f,b1=3e38f,b2=3e38f,b3=3e38f,b4=3e38f,b5=3e38f,
          b6=3e38f,b7=3e38f,b8=3e38f,b9=3e38f,b10=3e38f,b11=3e38f;
    int   j0=-1,j1=-1,j2=-1,j3=-1,j4=-1,j5=-1,j6=-1,j7=-1,j8=-1,j9=-1,j10=-1,j11=-1;
    for (int s = 0; s < KSEG; ++s) {
        const int n = cnt8[(size_t)s*NN + q];
        const size_t base = ((size_t)s*NN + q)*CAP;
        for (int i = 0; i < n; ++i) {
            int idx = pairs[base + i];
            if (idx == q) continue;                // self excluded (ref +1e9)
            float4 c = xw[idx];
            float dot = me.x*c.x + me.y*c.y + me.z*c.z;
            float d = fmaf(-2.0f, dot, qsq + c.w); // EXACT ref formula
            d = fmaxf(d, 0.0f);                    // ref clips at 0
            if (d < b11) KINSERT(d, idx);
        }
    }
    knn_idx[q*KNN+0]=j0;  knn_idx[q*KNN+1]=j1;  knn_idx[q*KNN+2]=j2;
    knn_idx[q*KNN+3]=j3;  knn_idx[q*KNN+4]=j4;  knn_idx[q*KNN+5]=j5;
    knn_idx[q*KNN+6]=j6;  knn_idx[q*KNN+7]=j7;  knn_idx[q*KNN+8]=j8;
    knn_idx[q*KNN+9]=j9;  knn_idx[q*KNN+10]=j10; knn_idx[q*KNN+11]=j11;
}

// ---------------- weight convert+transpose to f16 [N][K] ----------------
__global__ __launch_bounds__(256) void convert_Wt_kernel(const float* __restrict__ W,
                                                         _Float16* __restrict__ Wt) {
    int e = blockIdx.x*256 + threadIdx.x;
    int l = e >> 16, r = e & 65535;
    int n = r >> 8, k = r & 255;
    Wt[(size_t)l*65536 + n*256 + k] = (_Float16)W[(size_t)l*65536 + k*256 + n];
}

__global__ __launch_bounds__(256) void convert_Bg_kernel(const float* __restrict__ Ws,
                                                         const float* __restrict__ Wn,
                                                         _Float16* __restrict__ Bg) {
    int e = blockIdx.x*256 + threadIdx.x;
    int l = e / 73728, r = e % 73728;
    int n = r / 384, k = r % 384;
    float v = (k < 192) ? Ws[(size_t)l*36864 + k*192 + n]
                        : Wn[(size_t)l*36864 + (k-192)*192 + n];
    Bg[(size_t)l*73728 + (size_t)n*384 + k] = (_Float16)v;
}

__global__ __launch_bounds__(256) void convert_Wgo_kernel(const float* __restrict__ Wg_out,
                                                          _Float16* __restrict__ Wgo) {
    int e = blockIdx.x*256 + threadIdx.x;
    int n = e / 192, k = e % 192;
    Wgo[e] = (_Float16)Wg_out[k*256 + n];
}

// ---------------- fourier features + both input layers (f16 out) ----------------
__global__ __launch_bounds__(256) void fourier_input_kernel(
    const float* __restrict__ x, const float* __restrict__ Bf,
    const float* __restrict__ W_in, const float* __restrict__ b_in,
    const float* __restrict__ Wg_in, const float* __restrict__ bg_in,
    _Float16* __restrict__ h0, _Float16* __restrict__ g0) {
    const int n = blockIdx.x * 256 + threadIdx.x;
    const float x0 = x[3*n], x1 = x[3*n+1], x2 = x[3*n+2];
    float ff[FF];
#pragma unroll
    for (int sm = 0; sm < 24; ++sm) {
        int s = sm >> 3, m = sm & 7;
        float p = x0*Bf[s*24 + m] + x1*Bf[s*24 + 8 + m] + x2*Bf[s*24 + 16 + m];
        float sv, cv; sincosf(p, &sv, &cv);
        ff[sm] = sv; ff[24 + sm] = cv;
    }
    {
        const float4* W4 = (const float4*)W_in;
        const float4* b4 = (const float4*)b_in;
#pragma unroll 2
        for (int j4 = 0; j4 < WIDTH/4; ++j4) {
            float4 acc = b4[j4];
#pragma unroll
            for (int k = 0; k < FF; ++k) {
                float4 w = W4[k*(WIDTH/4) + j4]; float f = ff[k];
                acc.x = fmaf(f, w.x, acc.x); acc.y = fmaf(f, w.y, acc.y);
                acc.z = fmaf(f, w.z, acc.z); acc.w = fmaf(f, w.w, acc.w);
            }
            half4 o;
            o[0] = (_Float16)silu_f(acc.x); o[1] = (_Float16)silu_f(acc.y);
            o[2] = (_Float16)silu_f(acc.z); o[3] = (_Float16)silu_f(acc.w);
            *(half4*)&h0[(size_t)n*WIDTH + j4*4] = o;
        }
    }
    {
        const float4* W4 = (const float4*)Wg_in;
        const float4* b4 = (const float4*)bg_in;
#pragma unroll 2
        for (int j4 = 0; j4 < GW/4; ++j4) {
            float4 acc = b4[j4];
#pragma unroll
            for (int k = 0; k < FF; ++k) {
                float4 w = W4[k*(GW/4) + j4]; float f = ff[k];
                acc.x = fmaf(f, w.x, acc.x); acc.y = fmaf(f, w.y, acc.y);
                acc.z = fmaf(f, w.z, acc.z); acc.w = fmaf(f, w.w, acc.w);
            }
            half4 o;
            o[0] = (_Float16)silu_f(acc.x); o[1] = (_Float16)silu_f(acc.y);
            o[2] = (_Float16)silu_f(acc.z); o[3] = (_Float16)silu_f(acc.w);
            *(half4*)&g0[(size_t)n*GW + j4*4] = o;
        }
    }
}

// ---------------- gather + mean over 12 neighbors (f16) ----------------
__global__ __launch_bounds__(192) void gather_mean_kernel(const _Float16* __restrict__ g,
                                                          const int* __restrict__ idx,
                                                          _Float16* __restrict__ agg) {
    __shared__ int nb[KNN];
    const int n = blockIdx.x;
    if (threadIdx.x < KNN) nb[threadIdx.x] = idx[n*KNN + threadIdx.x];
    __syncthreads();
    float acc = 0.0f;
#pragma unroll
    for (int k = 0; k < KNN; ++k) acc += (float)g[(size_t)nb[k]*GW + threadIdx.x];
    agg[(size_t)n*GW + threadIdx.x] = (_Float16)(acc * (1.0f/12.0f));
}

// ---------------- FiLM params ----------------
__global__ __launch_bounds__(256) void film_kernel(const float* __restrict__ cond,
                                                   const float* __restrict__ Wf_g,
                                                   const float* __restrict__ bf_g,
                                                   const float* __restrict__ Wf_b,
                                                   const float* __restrict__ bf_b,
                                                   float* __restrict__ film) {
    const int l = blockIdx.x, j = threadIdx.x;
    float g = bf_g[l*WIDTH + j], b = bf_b[l*WIDTH + j];
    for (int c = 0; c < 64; ++c) {
        float cv = cond[c];
        g = fmaf(cv, Wf_g[(size_t)(l*64 + c)*WIDTH + j], g);
        b = fmaf(cv, Wf_b[(size_t)(l*64 + c)*WIDTH + j], b);
    }
    film[l*2*WIDTH + j]         = 1.0f + g;
    film[l*2*WIDTH + WIDTH + j] = b;
}

// ---------------- f16 MFMA GEMM: BM=128, BN=64, 4 waves ----------------
template<int EPI>
__global__ __launch_bounds__(256) void gemm_mfma(
    const _Float16* __restrict__ A1, const _Float16* __restrict__ A2,
    const _Float16* __restrict__ Bt, int K1, int Ktot, int NC,
    const float* __restrict__ bias, const float* __restrict__ film,
    const _Float16* __restrict__ h0, _Float16* __restrict__ C, int addSkip) {
    __shared__ _Float16 As[128*40];
    __shared__ _Float16 Bs[64*40];
    const int tid = threadIdx.x;
    const int bm = blockIdx.x * 128, bn = blockIdx.y * 64;
    const int wid = tid >> 6, lane = tid & 63;
    const int wm = (wid & 1) * 64, wn = (wid >> 1) * 32;
    const int m16 = lane & 15, kq = lane >> 4;
    const int ar = tid >> 1, ah = tid & 1;
    const int br = tid >> 2, bq = tid & 3;
    f4 acc[4][2];
#pragma unroll
    for (int i = 0; i < 4; ++i)
#pragma unroll
        for (int j = 0; j < 2; ++j) acc[i][j] = (f4){0.f, 0.f, 0.f, 0.f};

    for (int kc = 0; kc < Ktot; kc += 32) {
        const _Float16* Asrc; int kl, ldA;
        if (kc < K1) { Asrc = A1; kl = kc;      ldA = K1; }
        else         { Asrc = A2; kl = kc - K1; ldA = Ktot - K1; }
        {
            const float4* src = (const float4*)&Asrc[(size_t)(bm + ar)*ldA + kl + ah*16];
            *(float4*)&As[ar*40 + ah*16]     = src[0];
            *(float4*)&As[ar*40 + ah*16 + 8] = src[1];
        }
        *(float4*)&Bs[br*40 + bq*8] = *(const float4*)&Bt[(size_t)(bn + br)*Ktot + kc + bq*8];
        __syncthreads();
        half8 af[4], bf[2];
#pragma unroll
        for (int mt = 0; mt < 4; ++mt) af[mt] = *(half8*)&As[(wm + mt*16 + m16)*40 + kq*8];
#pragma unroll
        for (int nt = 0; nt < 2; ++nt) bf[nt] = *(half8*)&Bs[(wn + nt*16 + m16)*40 + kq*8];
#pragma unroll
        for (int mt = 0; mt < 4; ++mt)
#pragma unroll
            for (int nt = 0; nt < 2; ++nt)
                acc[mt][nt] = __builtin_amdgcn_mfma_f32_16x16x32_f16(af[mt], bf[nt], acc[mt][nt], 0, 0, 0);
        __syncthreads();
    }

#pragma unroll
    for (int mt = 0; mt < 4; ++mt) {
#pragma unroll
        for (int nt = 0; nt < 2; ++nt) {
            int col = bn + wn + nt*16 + m16;
#pragma unroll
            for (int r = 0; r < 4; ++r) {
                int row = bm + wm + mt*16 + kq*4 + r;
                float v = acc[mt][nt][r];
                if (EPI == 0) {
                    v = silu_f(v + bias[col]);
                } else if (EPI == 1) {
                    v = fmaf(v + bias[col], film[col], film[NC + col]);
                    v = silu_f(v);
                    if (addSkip) v += (float)h0[(size_t)row*NC + col];
                } else {
                    v += (float)h0[(size_t)row*NC + col];
                }
                C[(size_t)row*NC + col] = (_Float16)v;
            }
        }
    }
}

// ---------------- output head: (h @ W_out + b_out) * 0.01 ----------------
__global__ __launch_bounds__(256) void out_kernel(const _Float16* __restrict__ h,
                                                  const float* __restrict__ W_out,
                                                  const float* __restrict__ b_out,
                                                  float* __restrict__ out) {
    const int n = blockIdx.x * 256 + threadIdx.x;
    float a0 = 0.f, a1 = 0.f, a2 = 0.f;
#pragma unroll 4
    for (int k8 = 0; k8 < WIDTH/8; ++k8) {
        half8 v = *(const half8*)&h[(size_t)n*WIDTH + k8*8];
#pragma unroll
        for (int u = 0; u < 8; ++u) {
            float f = (float)v[u]; int k = k8*8 + u;
            a0 = fmaf(f, W_out[k*3+0], a0);
            a1 = fmaf(f, W_out[k*3+1], a1);
            a2 = fmaf(f, W_out[k*3+2], a2);
        }
    }
    out[n*3+0] = (a0 + b_out[0]) * 0.01f;
    out[n*3+1] = (a1 + b_out[1]) * 0.01f;
    out[n*3+2] = (a2 + b_out[2]) * 0.01f;
}

extern "C" void kernel_launch(void* const* d_in, const int* in_sizes, int n_in,
                              void* d_out, int out_size, void* d_ws, size_t ws_size,
                              hipStream_t stream) {
    const float* x      = (const float*)d_in[0];
    const float* cond   = (const float*)d_in[1];
    const float* Bf     = (const float*)d_in[2];
    const float* W_in   = (const float*)d_in[3];
    const float* b_in   = (const float*)d_in[4];
    const float* Wg_in  = (const float*)d_in[5];
    const float* bg_in  = (const float*)d_in[6];
    const float* Ws     = (const float*)d_in[7];
    const float* Wn     = (const float*)d_in[8];
    const float* bg     = (const float*)d_in[9];
    const float* Wg_out = (const float*)d_in[10];
    const float* W      = (const float*)d_in[11];
    const float* bmlp   = (const float*)d_in[12];
    const float* Wf_g   = (const float*)d_in[13];
    const float* bf_g   = (const float*)d_in[14];
    const float* Wf_b   = (const float*)d_in[15];
    const float* bf_b   = (const float*)d_in[16];
    const float* W_out  = (const float*)d_in[17];
    const float* b_out  = (const float*)d_in[18];
    float* out = (float*)d_out;

    char* ws = (char*)d_ws;
    int*       knn_idx = (int*)      (ws + 0);          //  3,145,728
    float4*    xw      = (float4*)   (ws + 3145728);    //  1,048,576
    float*     film    = (float*)    (ws + 4194304);    //     14,336
    _Float16*  Bg_t    = (_Float16*) (ws + 4210688);    //    589,824
    _Float16*  Wgo_t   = (_Float16*) (ws + 4800512);    //     98,304
    _Float16*  Wt      = (_Float16*) (ws + 4898816);    //    917,504
    _Float16*  h0      = (_Float16*) (ws + 5816320);    // 33,554,432 (f16)
    // SAT + seed overlay h0 region (dead before fourier_input writes h0)
    int*       cnt     = (int*)      (ws + 5816320);    // 28,311,552 (192^3 SAT in place)
    float*     seed    = (float*)    (ws + 34127872);   //    262,144
    _Float16*  g_a     = (_Float16*) (ws + 39370752);   // 25,165,824
    // pairs/cnt8 overlay g_a..hB region (all dead during kNN):
    // pairs u16 [seg][q][CAP]: NN*KSEG*CAP*2 = 117,440,512 -> 39,370,752..156,811,264
    unsigned short* pairs = (unsigned short*)(ws + 39370752);
    unsigned char*  cnt8  = (unsigned char*) (ws + 156811264);  // NN*KSEG = 2,097,152
    _Float16*  g_b     = (_Float16*) (ws + 64536576);   // 25,165,824
    _Float16*  agg     = (_Float16*) (ws + 89702400);   // 25,165,824
    _Float16*  hA      = (_Float16*) (ws + 114868224);  // 33,554,432
    _Float16*  hB      = (_Float16*) (ws + 148422656);  // 33,554,432 -> ends 181,977,088

    // --- kNN: SAT seed -> QPT=8 pair scan (dense writes) -> tiny exact top-12 ---
    prep_xw_kernel<<<NN/256, 256, 0, stream>>>(x, xw);
    zero_cnt_kernel<<<GC3/1024, 256, 0, stream>>>(cnt);
    hist_kernel<<<NN/256, 256, 0, stream>>>(xw, cnt);
    satx_kernel<<<GC*GC/256, 256, 0, stream>>>(cnt);
    saty_kernel<<<GC*GC/256, 256, 0, stream>>>(cnt);
    satz_kernel<<<GC*GC/256, 256, 0, stream>>>(cnt);
    seed_kernel<<<NN/256, 256, 0, stream>>>(xw, cnt, seed);
    knn_pairs_kernel<<<dim3(NN/(256*QPT), KSEG), 256, 0, stream>>>(xw, seed, pairs, cnt8);
    knn_topk_kernel<<<NN/256, 256, 0, stream>>>(xw, cnt8, pairs, knn_idx);

    // --- network ---
    film_kernel<<<DEPTH, 256, 0, stream>>>(cond, Wf_g, bf_g, Wf_b, bf_b, film);
    convert_Wt_kernel<<<DEPTH*65536/256, 256, 0, stream>>>(W, Wt);
    convert_Bg_kernel<<<GLAYERS*73728/256, 256, 0, stream>>>(Ws, Wn, Bg_t);
    convert_Wgo_kernel<<<256*192/256, 256, 0, stream>>>(Wg_out, Wgo_t);
    fourier_input_kernel<<<NN/256, 256, 0, stream>>>(x, Bf, W_in, b_in, Wg_in, bg_in, h0, g_a);

    _Float16* gin = g_a; _Float16* gout = g_b;
    for (int l = 0; l < GLAYERS; ++l) {
        gather_mean_kernel<<<NN, GW, 0, stream>>>(gin, knn_idx, agg);
        gemm_mfma<0><<<dim3(NN/128, GW/64), 256, 0, stream>>>(
            gin, agg, Bg_t + (size_t)l*73728, GW, 2*GW, GW,
            bg + l*GW, nullptr, nullptr, gout, 0);
        _Float16* t = gin; gin = gout; gout = t;
    }
    // gin == g_a (4 swaps). inject: hA = h0 + gin @ Wg_out
    gemm_mfma<2><<<dim3(NN/128, WIDTH/64), 256, 0, stream>>>(
        gin, nullptr, Wgo_t, GW, GW, WIDTH, nullptr, nullptr, h0, hA, 0);

    _Float16* hin = hA; _Float16* hout = hB;
    for (int l = 0; l < DEPTH; ++l) {
        int skip = (l == 2 || l == 5) ? 1 : 0;   // SKIPS=(3,6): after layers idx 2,5
        gemm_mfma<1><<<dim3(NN/128, WIDTH/64), 256, 0, stream>>>(
            hin, nullptr, Wt + (size_t)l*65536, WIDTH, WIDTH, WIDTH,
            bmlp + l*WIDTH, film + l*2*WIDTH, h0, hout, skip);
        _Float16* t = hin; hin = hout; hout = t;
    }
    out_kernel<<<NN/256, 256, 0, stream>>>(hin, W_out, b_out, out);
}